// Round 20
// baseline (74.337 us; speedup 1.0000x reference)
//
#include <hip/hip_runtime.h>
#include <hip/hip_bf16.h>
#include <stdint.h>

#define B_    4
#define N_    4096
#define FIN   64
#define NPROP 64
#define NFILT 128
#define KSEL  40
#define ROWS  (B_ * N_)
#define CAP   160
#define CAPP  176

typedef __attribute__((ext_vector_type(8)))  short short8;
typedef __attribute__((ext_vector_type(4)))  float f32x4;
typedef __attribute__((ext_vector_type(16))) float f32x16;

__device__ __forceinline__ unsigned b16rne(float v) {
    unsigned u = __float_as_uint(v);
    return (u + 0x7FFFu + ((u >> 16) & 1u)) >> 16;
}
__device__ __forceinline__ float fromb16(unsigned h) {
    return __uint_as_float(h << 16);
}
// multiply both packed bf16 halves by -2 (sign flip + exponent+1); exact
__device__ __forceinline__ unsigned neg2pk(unsigned p) {
    return (p + 0x00800080u) ^ 0x80008000u;
}
__device__ __forceinline__ uint2 pk4(unsigned a, unsigned b, unsigned c, unsigned d) {
    return make_uint2(a | (b << 16), c | (d << 16));
}

// ---------------- K01: merged projections + W_out pack --------------------
// blocks 0..255  : k1 MFMA projections (validated math), W frags inline.
// blocks 256..383: Wpk pack (consumed only by k2 -> no race).
__global__ __launch_bounds__(256) void k01_proj(
    const float* __restrict__ x,  const float* __restrict__ Wf,
    const float* __restrict__ bf, const float* __restrict__ Ws,
    const float* __restrict__ bs, const float* __restrict__ Wo,
    float* __restrict__ feat, uint4* __restrict__ Bpk,
    unsigned short* __restrict__ Wpk)
{
    int bid = blockIdx.x;

    if (bid >= 256) {                        // ---- Wpk pack ----
        int c = bid - 256, k = threadIdx.x;
        if (k < 192) {
            float wv2 = Wo[k * NFILT + c];
            unsigned wh = b16rne(wv2);
            unsigned wl = b16rne(wv2 - fromb16(wh));
            Wpk[(size_t)c * 576 + k]       = (unsigned short)wh;
            Wpk[(size_t)c * 576 + 192 + k] = (unsigned short)wh;
            Wpk[(size_t)c * 576 + 384 + k] = (unsigned short)wl;
        }
        return;
    }

    // ---- k1 projections (4 waves x 16 rows) ----
    __shared__ float clds[4][16][20];
    int wv = threadIdx.x >> 6, lane = threadIdx.x & 63;
    int li = lane & 15, g = lane >> 4;
    int rbase = bid * 64 + wv * 16;

    const float* xr = x + (size_t)(rbase + li) * FIN + 8 * g;
    float4 a0 = *reinterpret_cast<const float4*>(xr);
    float4 a1 = *reinterpret_cast<const float4*>(xr + 4);
    float4 b0 = *reinterpret_cast<const float4*>(xr + 32);
    float4 b1 = *reinterpret_cast<const float4*>(xr + 36);

    float av[8] = {a0.x, a0.y, a0.z, a0.w, a1.x, a1.y, a1.z, a1.w};
    float bv[8] = {b0.x, b0.y, b0.z, b0.w, b1.x, b1.y, b1.z, b1.w};
    unsigned xh01u[4], xl01u[4], xh23u[4], xl23u[4];
    #pragma unroll
    for (int p = 0; p < 4; ++p) {
        unsigned h0 = b16rne(av[2 * p]), h1 = b16rne(av[2 * p + 1]);
        xh01u[p] = h0 | (h1 << 16);
        xl01u[p] = b16rne(av[2 * p] - fromb16(h0)) | (b16rne(av[2 * p + 1] - fromb16(h1)) << 16);
        unsigned g0 = b16rne(bv[2 * p]), g1 = b16rne(bv[2 * p + 1]);
        xh23u[p] = g0 | (g1 << 16);
        xl23u[p] = b16rne(bv[2 * p] - fromb16(g0)) | (b16rne(bv[2 * p + 1] - fromb16(g1)) << 16);
    }
    union { uint4 u; short8 s; } XH01, XL01, XH23, XL23;
    XH01.u = make_uint4(xh01u[0], xh01u[1], xh01u[2], xh01u[3]);
    XL01.u = make_uint4(xl01u[0], xl01u[1], xl01u[2], xl01u[3]);
    XH23.u = make_uint4(xh23u[0], xh23u[1], xh23u[2], xh23u[3]);
    XL23.u = make_uint4(xl23u[0], xl23u[1], xl23u[2], xl23u[3]);

    #pragma unroll 1
    for (int ct = 0; ct < 4; ++ct) {
        unsigned whA[4], whB[4], wlA[4], wlB[4];
        #pragma unroll
        for (int p = 0; p < 4; ++p) {
            float v0 = Wf[(8 * g + 2 * p)          * NPROP + ct * 16 + li];
            float v1 = Wf[(8 * g + 2 * p + 1)      * NPROP + ct * 16 + li];
            float u0 = Wf[(32 + 8 * g + 2 * p)     * NPROP + ct * 16 + li];
            float u1 = Wf[(32 + 8 * g + 2 * p + 1) * NPROP + ct * 16 + li];
            unsigned h0 = b16rne(v0), h1 = b16rne(v1);
            unsigned k0 = b16rne(u0), k1 = b16rne(u1);
            whA[p] = h0 | (h1 << 16);
            whB[p] = k0 | (k1 << 16);
            wlA[p] = b16rne(v0 - fromb16(h0)) | (b16rne(v1 - fromb16(h1)) << 16);
            wlB[p] = b16rne(u0 - fromb16(k0)) | (b16rne(u1 - fromb16(k1)) << 16);
        }
        union { uint4 u; short8 s; } WA, WB, LA, LB;
        WA.u = make_uint4(whA[0], whA[1], whA[2], whA[3]);
        WB.u = make_uint4(whB[0], whB[1], whB[2], whB[3]);
        LA.u = make_uint4(wlA[0], wlA[1], wlA[2], wlA[3]);
        LB.u = make_uint4(wlB[0], wlB[1], wlB[2], wlB[3]);
        float bfv = bf[ct * 16 + li];
        f32x4 acc = {bfv, bfv, bfv, bfv};
        acc = __builtin_amdgcn_mfma_f32_16x16x32_bf16(XH01.s, WA.s, acc, 0, 0, 0);
        acc = __builtin_amdgcn_mfma_f32_16x16x32_bf16(XH23.s, WB.s, acc, 0, 0, 0);
        acc = __builtin_amdgcn_mfma_f32_16x16x32_bf16(XL01.s, WA.s, acc, 0, 0, 0);
        acc = __builtin_amdgcn_mfma_f32_16x16x32_bf16(XL23.s, WB.s, acc, 0, 0, 0);
        acc = __builtin_amdgcn_mfma_f32_16x16x32_bf16(XH01.s, LA.s, acc, 0, 0, 0);
        acc = __builtin_amdgcn_mfma_f32_16x16x32_bf16(XH23.s, LB.s, acc, 0, 0, 0);
        #pragma unroll
        for (int e = 0; e < 4; ++e)
            feat[(size_t)(rbase + g * 4 + e) * NPROP + ct * 16 + li] = acc[e];
    }

    {
        unsigned whA[4], whB[4], wlA[4], wlB[4];
        #pragma unroll
        for (int p = 0; p < 4; ++p) {
            float v0 = (li < 4) ? Ws[(8 * g + 2 * p)          * 4 + li] : 0.f;
            float v1 = (li < 4) ? Ws[(8 * g + 2 * p + 1)      * 4 + li] : 0.f;
            float u0 = (li < 4) ? Ws[(32 + 8 * g + 2 * p)     * 4 + li] : 0.f;
            float u1 = (li < 4) ? Ws[(32 + 8 * g + 2 * p + 1) * 4 + li] : 0.f;
            unsigned h0 = b16rne(v0), h1 = b16rne(v1);
            unsigned k0 = b16rne(u0), k1 = b16rne(u1);
            whA[p] = h0 | (h1 << 16);
            whB[p] = k0 | (k1 << 16);
            wlA[p] = b16rne(v0 - fromb16(h0)) | (b16rne(v1 - fromb16(h1)) << 16);
            wlB[p] = b16rne(u0 - fromb16(k0)) | (b16rne(u1 - fromb16(k1)) << 16);
        }
        union { uint4 u; short8 s; } WA, WB, LA, LB;
        WA.u = make_uint4(whA[0], whA[1], whA[2], whA[3]);
        WB.u = make_uint4(whB[0], whB[1], whB[2], whB[3]);
        LA.u = make_uint4(wlA[0], wlA[1], wlA[2], wlA[3]);
        LB.u = make_uint4(wlB[0], wlB[1], wlB[2], wlB[3]);
        float bsv = (li < 4) ? bs[li] : 0.f;
        f32x4 acc = {bsv, bsv, bsv, bsv};
        acc = __builtin_amdgcn_mfma_f32_16x16x32_bf16(XH01.s, WA.s, acc, 0, 0, 0);
        acc = __builtin_amdgcn_mfma_f32_16x16x32_bf16(XH23.s, WB.s, acc, 0, 0, 0);
        acc = __builtin_amdgcn_mfma_f32_16x16x32_bf16(XL01.s, WA.s, acc, 0, 0, 0);
        acc = __builtin_amdgcn_mfma_f32_16x16x32_bf16(XL23.s, WB.s, acc, 0, 0, 0);
        acc = __builtin_amdgcn_mfma_f32_16x16x32_bf16(XH01.s, LA.s, acc, 0, 0, 0);
        acc = __builtin_amdgcn_mfma_f32_16x16x32_bf16(XH23.s, LB.s, acc, 0, 0, 0);
        if (li < 4) {
            #pragma unroll
            for (int e = 0; e < 4; ++e) clds[wv][g * 4 + e][li] = acc[e];
        }
    }
    __syncthreads();

    if (lane < 16) {
        int row = rbase + lane;
        float c0 = clds[wv][lane][0], c1 = clds[wv][lane][1];
        float c2 = clds[wv][lane][2], c3 = clds[wv][lane][3];
        unsigned h0 = b16rne(c0), h1 = b16rne(c1), h2 = b16rne(c2), h3 = b16rne(c3);
        unsigned l0 = b16rne(c0 - fromb16(h0)), l1 = b16rne(c1 - fromb16(h1));
        unsigned l2 = b16rne(c2 - fromb16(h2)), l3 = b16rne(c3 - fromb16(h3));
        float n = c0 * c0; n = fmaf(c1, c1, n); n = fmaf(c2, c2, n); n = fmaf(c3, c3, n);
        unsigned nih = b16rne(n), nil = b16rne(n - fromb16(nih));
        unsigned v0 = h0 | (h1 << 16), v1 = h2 | (h3 << 16);
        unsigned v4 = l0 | (l1 << 16), v5 = l2 | (l3 << 16);
        Bpk[(size_t)row * 2 + 0] = make_uint4(v0, v1, v0, v1);
        Bpk[(size_t)row * 2 + 1] = make_uint4(v4, v5, 0x3F803F80u, nih | (nil << 16));
    }
}

// ---------------- K2: 32x32x16-MFMA KNN top-40 + fused output GEMM --------
// FROZEN structure (61.3us) + XCD remap (R19). This round, latency-hiding
// only: (1) P4b batch-reads composites + precomputes exp weights before the
// gather loop; (2) P4a x-loads and epilogue bo hoisted above pass 2. VGPR
// headroom: 32 -> ~56 of the 64 budget.
__global__ __launch_bounds__(1024, 8) void k2_knn(
    const uint4* __restrict__ Bpk, const float* __restrict__ feat,
    const float* __restrict__ x, const unsigned short* __restrict__ Wpk,
    const float* __restrict__ bo, float* __restrict__ out)
{
    __shared__ unsigned minlds[32][132];      // 16896 B
    __shared__ unsigned survK[32][CAPP];      // 22528 B
    __shared__ unsigned taulds[32];
    __shared__ int      cnt[32];
    __shared__ unsigned winC[32][KSEL];       //  5120 B
    __shared__ unsigned short Upk[32][392];   // 25088 B

    int tid = threadIdx.x, w = tid >> 6, lane = tid & 63;
    int bid   = blockIdx.x;
    int xcd   = bid & 7;
    int b     = xcd & 3;                      // batch pinned per XCD
    int strip = (bid >> 3) * 2 + (xcd >> 2);
    int q0    = strip * 32;
    int col = lane & 31, h = lane >> 5;
    int g = lane >> 4, li = lane & 15;        // epilogue indices (16x16x32 D)
    size_t pbase = (size_t)b * N_;

    if (tid < 32) cnt[tid] = 0;

    // A fragment: query q0+col, k-half h
    short8 afr;
    {
        uint4 u0 = Bpk[(pbase + q0 + col) * 2 + 0];
        uint4 u1 = Bpk[(pbase + q0 + col) * 2 + 1];
        union { uint4 u; short8 s; } cv;
        cv.u = (h == 0) ? make_uint4(neg2pk(u0.x), neg2pk(u0.y), neg2pk(u1.x), neg2pk(u1.y))
                        : make_uint4(neg2pk(u0.x), neg2pk(u0.y), u1.w, u1.z);
        afr = cv.s;
    }

    const uint4* bp = Bpk + (pbase + w * 256 + col) * 2 + h;

    // ---- pass 1: MFMA + per-row float minima (8 tiles, 2-deep prefetch) --
    float fm[16];
    #pragma unroll
    for (int r = 0; r < 16; ++r) fm[r] = 1e30f;
    uint4 nb0 = bp[0], nb1 = bp[64];
    #pragma unroll
    for (int t = 0; t < 8; ++t) {
        union { uint4 u; short8 s; } bvv; bvv.u = nb0;
        nb0 = nb1;
        if (t + 2 < 8) nb1 = bp[(t + 2) * 64];
        f32x16 d = __builtin_amdgcn_mfma_f32_32x32x16_bf16(afr, bvv.s, (f32x16){0.f}, 0, 0, 0);
        #pragma unroll
        for (int r = 0; r < 16; ++r) fm[r] = fminf(fm[r], d[r]);
    }
    #pragma unroll
    for (int r = 0; r < 16; ++r) {
        float v = fm[r];
        v = fminf(v, __shfl_xor(v, 8));
        v = fminf(v, __shfl_xor(v, 16));
        fm[r] = v;
    }
    if ((lane & 24) == 0) {
        #pragma unroll
        for (int r = 0; r < 16; ++r) {
            int row = (r & 3) + 8 * (r >> 2) + 4 * h;
            minlds[row][w * 8 + (lane & 7)] = __float_as_uint(fmaxf(fm[r], 0.0f));
        }
    }
    __syncthreads();

    // ---- tau: merge 128 -> 64 group minima, bitonic-64, take #39 ----
    unsigned sv[2];
    #pragma unroll
    for (int e = 0; e < 2; ++e) {
        int r = 2 * w + e;
        sv[e] = min(minlds[r][lane], minlds[r][64 + lane]);
    }
    #pragma unroll
    for (int k = 2; k <= 64; k <<= 1) {
        #pragma unroll
        for (int j2 = k >> 1; j2 >= 1; j2 >>= 1) {
            bool up = (((lane & k) == 0) == ((lane & j2) == 0));
            #pragma unroll
            for (int e = 0; e < 2; ++e) {
                unsigned o = (unsigned)__shfl_xor((int)sv[e], j2);
                sv[e] = up ? min(sv[e], o) : max(sv[e], o);
            }
        }
    }
    if (lane == 39) {
        taulds[2 * w]     = (sv[0] & 0xFFFFF000u) | 0xFFFu;
        taulds[2 * w + 1] = (sv[1] & 0xFFFFF000u) | 0xFFFu;
    }
    __syncthreads();

    float tauF[16];
    #pragma unroll
    for (int r = 0; r < 16; ++r)
        tauF[r] = __uint_as_float(taulds[(r & 3) + 8 * (r >> 2) + 4 * h]);

    // hoisted: x rows for P4a + epilogue bias (in flight across pass2+rank)
    float xpre0 = x[(pbase + q0 + 2 * w) * FIN + lane];
    float xpre1 = x[(pbase + q0 + 2 * w + 1) * FIN + lane];
    float bb    = bo[(w & 7) * 16 + li];

    bool selfDiag = (h == ((col >> 2) & 1));
    int  rs       = ((col >> 3) << 2) | (col & 3);
    int  tdiag    = (w == (strip >> 3)) ? (strip & 7) : 99;    // uniform per wave

    // ---- pass 2: re-stream via MFMA (2-deep prefetch), float-cmp drain ----
    nb0 = bp[0]; nb1 = bp[64];
    #pragma unroll
    for (int t = 0; t < 8; ++t) {
        union { uint4 u; short8 s; } bvv; bvv.u = nb0;
        nb0 = nb1;
        if (t + 2 < 8) nb1 = bp[(t + 2) * 64];
        f32x16 d = __builtin_amdgcn_mfma_f32_32x32x16_bf16(afr, bvv.s, (f32x16){0.f}, 0, 0, 0);
        unsigned idx = (unsigned)((w * 8 + t) * 32 + col);
        if (t == tdiag) {                                      // uniform: diag tile
            #pragma unroll
            for (int r = 0; r < 16; ++r) {
                int rowc = (r & 3) + 8 * (r >> 2) + 4 * h;
                if (selfDiag && r == rs) {                     // self -> rank 0
                    int s = atomicAdd(&cnt[rowc], 1); if (s < CAP) survK[rowc][s] = 0u;
                } else if (d[r] <= tauF[r]) {
                    unsigned c = (__float_as_uint(fmaxf(d[r], 0.f)) & 0xFFFFF000u) | idx;
                    int s = atomicAdd(&cnt[rowc], 1); if (s < CAP) survK[rowc][s] = c;
                }
            }
        } else {
            #pragma unroll
            for (int r = 0; r < 16; ++r) {
                if (d[r] <= tauF[r]) {
                    int rowc = (r & 3) + 8 * (r >> 2) + 4 * h;
                    unsigned c = (__float_as_uint(fmaxf(d[r], 0.f)) & 0xFFFFF000u) | idx;
                    int s = atomicAdd(&cnt[rowc], 1); if (s < CAP) survK[rowc][s] = c;
                }
            }
        }
    }
    __syncthreads();

    // ---- rank survivors; ranks 1..39 -> winners (2 rows per wave) ----
    #pragma unroll
    for (int e = 0; e < 2; ++e) {
        int r = 2 * w + e;
        int S = min(cnt[r], CAP);
        if (lane < 16) survK[r][S + lane] = 0xFFFFFFFFu;       // sentinels
        for (int rr = lane; rr < S; rr += 64) {
            unsigned my = survK[r][rr];
            int c = 0;
            int S4 = (S + 3) >> 2;
            for (int s4 = 0; s4 < S4; ++s4) {
                uint4 u4 = *reinterpret_cast<const uint4*>(&survK[r][4 * s4]);
                c += (u4.x < my) + (u4.y < my) + (u4.z < my) + (u4.w < my);
            }
            if (c >= 1 && c < KSEL) winC[r][c - 1] = my;
        }
    }
    // no barrier: P4 consumes only this wave's own rows (LDS same-wave RAW)

    // ---- P4a: x hi/lo pack (full wave per row, loads hoisted) ----
    {
        unsigned xh0 = b16rne(xpre0), xl0 = b16rne(xpre0 - fromb16(xh0));
        unsigned xh1 = b16rne(xpre1), xl1 = b16rne(xpre1 - fromb16(xh1));
        Upk[2 * w][lane]           = (unsigned short)xh0;
        Upk[2 * w][192 + lane]     = (unsigned short)xl0;
        Upk[2 * w + 1][lane]       = (unsigned short)xh1;
        Upk[2 * w + 1][192 + lane] = (unsigned short)xl1;
    }

    // ---- P4b: neighbor-parallel aggregation; weights precomputed --------
    {
        int l15 = lane & 15;
        int gi  = (lane >> 4) & 1;
        int rw  = 2 * w + (lane >> 5);
        const float4* fr = reinterpret_cast<const float4*>(feat + pbase * NPROP);
        float4 mx4 = make_float4(-3.4e38f, -3.4e38f, -3.4e38f, -3.4e38f);
        float4 sm4 = make_float4(0.f, 0.f, 0.f, 0.f);
        int base = gi * 20;

        // chunk 0: neighbors base+0 .. base+11 (all valid)
        {
            unsigned cp[12]; float wt[12];
            #pragma unroll
            for (int u = 0; u < 3; ++u) {
                uint4 c4 = *reinterpret_cast<const uint4*>(&winC[rw][base + 4 * u]);
                cp[4 * u] = c4.x; cp[4 * u + 1] = c4.y; cp[4 * u + 2] = c4.z; cp[4 * u + 3] = c4.w;
            }
            #pragma unroll
            for (int i = 0; i < 12; ++i)
                wt[i] = __expf(-10.f * __uint_as_float(cp[i] & 0xFFFFF000u));
            #pragma unroll
            for (int i = 0; i < 12; ++i) {
                float4 f4 = fr[(int)(cp[i] & 0xFFFu) * 16 + l15];
                float wx = wt[i] * f4.x, wy = wt[i] * f4.y, wz = wt[i] * f4.z, ww = wt[i] * f4.w;
                mx4.x = fmaxf(mx4.x, wx); sm4.x += wx;
                mx4.y = fmaxf(mx4.y, wy); sm4.y += wy;
                mx4.z = fmaxf(mx4.z, wz); sm4.z += wz;
                mx4.w = fmaxf(mx4.w, ww); sm4.w += ww;
            }
        }
        // chunk 1: neighbors base+12 .. base+19 (last invalid for gi==1)
        {
            unsigned cp[8]; float wt[8];
            #pragma unroll
            for (int u = 0; u < 2; ++u) {
                uint4 c4 = *reinterpret_cast<const uint4*>(&winC[rw][base + 12 + 4 * u]);
                cp[4 * u] = c4.x; cp[4 * u + 1] = c4.y; cp[4 * u + 2] = c4.z; cp[4 * u + 3] = c4.w;
            }
            #pragma unroll
            for (int i = 0; i < 8; ++i)
                wt[i] = __expf(-10.f * __uint_as_float(cp[i] & 0xFFFFF000u));
            if (gi) wt[7] = 0.f;                               // n==39 slot: sum-neutral
            #pragma unroll
            for (int i = 0; i < 8; ++i) {
                float4 f4 = fr[(int)(cp[i] & 0xFFFu) * 16 + l15];
                float wx = wt[i] * f4.x, wy = wt[i] * f4.y, wz = wt[i] * f4.z, ww = wt[i] * f4.w;
                sm4.x += wx; sm4.y += wy; sm4.z += wz; sm4.w += ww;
                if (i == 7) {                                  // mask max on invalid slot
                    float nf = -3.4e38f;
                    wx = gi ? nf : wx; wy = gi ? nf : wy;
                    wz = gi ? nf : wz; ww = gi ? nf : ww;
                }
                mx4.x = fmaxf(mx4.x, wx);
                mx4.y = fmaxf(mx4.y, wy);
                mx4.z = fmaxf(mx4.z, wz);
                mx4.w = fmaxf(mx4.w, ww);
            }
        }
        mx4.x = fmaxf(mx4.x, __shfl_xor(mx4.x, 16)); sm4.x += __shfl_xor(sm4.x, 16);
        mx4.y = fmaxf(mx4.y, __shfl_xor(mx4.y, 16)); sm4.y += __shfl_xor(sm4.y, 16);
        mx4.z = fmaxf(mx4.z, __shfl_xor(mx4.z, 16)); sm4.z += __shfl_xor(sm4.z, 16);
        mx4.w = fmaxf(mx4.w, __shfl_xor(mx4.w, 16)); sm4.w += __shfl_xor(sm4.w, 16);

        if (gi == 0) {
            unsigned h0 = b16rne(mx4.x), h1 = b16rne(mx4.y), h2 = b16rne(mx4.z), h3 = b16rne(mx4.w);
            unsigned o0 = b16rne(mx4.x - fromb16(h0)), o1 = b16rne(mx4.y - fromb16(h1));
            unsigned o2 = b16rne(mx4.z - fromb16(h2)), o3 = b16rne(mx4.w - fromb16(h3));
            *reinterpret_cast<uint2*>(&Upk[rw][64  + 4 * l15]) = pk4(h0, h1, h2, h3);
            *reinterpret_cast<uint2*>(&Upk[rw][256 + 4 * l15]) = pk4(o0, o1, o2, o3);
        } else {
            float ex = sm4.x * (1.0f / 39.0f), ey = sm4.y * (1.0f / 39.0f);
            float ez = sm4.z * (1.0f / 39.0f), ew = sm4.w * (1.0f / 39.0f);
            unsigned h0 = b16rne(ex), h1 = b16rne(ey), h2 = b16rne(ez), h3 = b16rne(ew);
            unsigned o0 = b16rne(ex - fromb16(h0)), o1 = b16rne(ey - fromb16(h1));
            unsigned o2 = b16rne(ez - fromb16(h2)), o3 = b16rne(ew - fromb16(h3));
            *reinterpret_cast<uint2*>(&Upk[rw][128 + 4 * l15]) = pk4(h0, h1, h2, h3);
            *reinterpret_cast<uint2*>(&Upk[rw][320 + 4 * l15]) = pk4(o0, o1, o2, o3);
        }
    }
    __syncthreads();

    // ---- epilogue: out[32 x 128] = U @ W_out + b_out; 16 waves, one
    //      16x16 out-tile each ----
    {
        int rh   = w >> 3;
        int colc = (w & 7) * 16 + li;
        const unsigned short* wp = Wpk + (size_t)colc * 576;
        f32x4 oacc = {0.f, 0.f, 0.f, 0.f};
        #pragma unroll
        for (int s = 0; s < 18; ++s) {
            int koff = (s < 6)  ? (32 * s + 8 * g)
                     : (s < 12) ? (192 + 32 * (s - 6) + 8 * g)
                                : (32 * (s - 12) + 8 * g);
            union { uint4 u; short8 s8; } av, bvv;
            av.u  = *reinterpret_cast<const uint4*>(&Upk[rh * 16 + li][koff]);
            bvv.u = *reinterpret_cast<const uint4*>(&wp[32 * s + 8 * g]);
            oacc = __builtin_amdgcn_mfma_f32_16x16x32_bf16(av.s8, bvv.s8, oacc, 0, 0, 0);
        }
        #pragma unroll
        for (int e = 0; e < 4; ++e) {
            int orow = rh * 16 + g * 4 + e;
            out[(size_t)(pbase + q0 + orow) * NFILT + colc] = oacc[e] + bb;
        }
    }
}

extern "C" void kernel_launch(void* const* d_in, const int* in_sizes, int n_in,
                              void* d_out, int out_size, void* d_ws, size_t ws_size,
                              hipStream_t stream)
{
    const float* x  = (const float*)d_in[0];
    const float* Wf = (const float*)d_in[1];
    const float* bf = (const float*)d_in[2];
    const float* Ws = (const float*)d_in[3];
    const float* bs = (const float*)d_in[4];
    const float* Wo = (const float*)d_in[5];
    const float* bo = (const float*)d_in[6];
    float* out = (float*)d_out;

    char* wsb = (char*)d_ws;
    float*          feat = (float*)wsb;                                  // 4 MB
    uint4*          Bpk  = (uint4*)(wsb + (size_t)ROWS * NPROP * 4);     // 512 KB
    unsigned short* Wpk  = (unsigned short*)(wsb + (size_t)ROWS * NPROP * 4
                                                 + (size_t)ROWS * 32);   // 144 KB

    k01_proj<<<384, 256, 0, stream>>>(x, Wf, bf, Ws, bs, Wo, feat, Bpk, Wpk);
    k2_knn  <<<B_ * 128, 1024, 0, stream>>>(Bpk, feat, x, Wpk, bo, out);
}

// Round 21
// 69.724 us; speedup vs baseline: 1.0662x; 1.0662x over previous
//
#include <hip/hip_runtime.h>
#include <hip/hip_bf16.h>
#include <stdint.h>

#define B_    4
#define N_    4096
#define FIN   64
#define NPROP 64
#define NFILT 128
#define KSEL  40
#define ROWS  (B_ * N_)
#define CAP   160
#define CAPP  176

typedef __attribute__((ext_vector_type(8)))  short short8;
typedef __attribute__((ext_vector_type(4)))  float f32x4;
typedef __attribute__((ext_vector_type(16))) float f32x16;

__device__ __forceinline__ unsigned b16rne(float v) {
    unsigned u = __float_as_uint(v);
    return (u + 0x7FFFu + ((u >> 16) & 1u)) >> 16;
}
__device__ __forceinline__ float fromb16(unsigned h) {
    return __uint_as_float(h << 16);
}
// multiply both packed bf16 halves by -2 (sign flip + exponent+1); exact
__device__ __forceinline__ unsigned neg2pk(unsigned p) {
    return (p + 0x00800080u) ^ 0x80008000u;
}
__device__ __forceinline__ uint2 pk4(unsigned a, unsigned b, unsigned c, unsigned d) {
    return make_uint2(a | (b << 16), c | (d << 16));
}

// ---------------- K01: merged projections + W_out pack --------------------
// blocks 0..255  : k1 MFMA projections (validated math), W frags inline.
// blocks 256..383: Wpk pack (consumed only by k2 -> no race).
__global__ __launch_bounds__(256) void k01_proj(
    const float* __restrict__ x,  const float* __restrict__ Wf,
    const float* __restrict__ bf, const float* __restrict__ Ws,
    const float* __restrict__ bs, const float* __restrict__ Wo,
    float* __restrict__ feat, uint4* __restrict__ Bpk,
    unsigned short* __restrict__ Wpk)
{
    int bid = blockIdx.x;

    if (bid >= 256) {                        // ---- Wpk pack ----
        int c = bid - 256, k = threadIdx.x;
        if (k < 192) {
            float wv2 = Wo[k * NFILT + c];
            unsigned wh = b16rne(wv2);
            unsigned wl = b16rne(wv2 - fromb16(wh));
            Wpk[(size_t)c * 576 + k]       = (unsigned short)wh;
            Wpk[(size_t)c * 576 + 192 + k] = (unsigned short)wh;
            Wpk[(size_t)c * 576 + 384 + k] = (unsigned short)wl;
        }
        return;
    }

    // ---- k1 projections (4 waves x 16 rows) ----
    __shared__ float clds[4][16][20];
    int wv = threadIdx.x >> 6, lane = threadIdx.x & 63;
    int li = lane & 15, g = lane >> 4;
    int rbase = bid * 64 + wv * 16;

    const float* xr = x + (size_t)(rbase + li) * FIN + 8 * g;
    float4 a0 = *reinterpret_cast<const float4*>(xr);
    float4 a1 = *reinterpret_cast<const float4*>(xr + 4);
    float4 b0 = *reinterpret_cast<const float4*>(xr + 32);
    float4 b1 = *reinterpret_cast<const float4*>(xr + 36);

    float av[8] = {a0.x, a0.y, a0.z, a0.w, a1.x, a1.y, a1.z, a1.w};
    float bv[8] = {b0.x, b0.y, b0.z, b0.w, b1.x, b1.y, b1.z, b1.w};
    unsigned xh01u[4], xl01u[4], xh23u[4], xl23u[4];
    #pragma unroll
    for (int p = 0; p < 4; ++p) {
        unsigned h0 = b16rne(av[2 * p]), h1 = b16rne(av[2 * p + 1]);
        xh01u[p] = h0 | (h1 << 16);
        xl01u[p] = b16rne(av[2 * p] - fromb16(h0)) | (b16rne(av[2 * p + 1] - fromb16(h1)) << 16);
        unsigned g0 = b16rne(bv[2 * p]), g1 = b16rne(bv[2 * p + 1]);
        xh23u[p] = g0 | (g1 << 16);
        xl23u[p] = b16rne(bv[2 * p] - fromb16(g0)) | (b16rne(bv[2 * p + 1] - fromb16(g1)) << 16);
    }
    union { uint4 u; short8 s; } XH01, XL01, XH23, XL23;
    XH01.u = make_uint4(xh01u[0], xh01u[1], xh01u[2], xh01u[3]);
    XL01.u = make_uint4(xl01u[0], xl01u[1], xl01u[2], xl01u[3]);
    XH23.u = make_uint4(xh23u[0], xh23u[1], xh23u[2], xh23u[3]);
    XL23.u = make_uint4(xl23u[0], xl23u[1], xl23u[2], xl23u[3]);

    #pragma unroll 1
    for (int ct = 0; ct < 4; ++ct) {
        unsigned whA[4], whB[4], wlA[4], wlB[4];
        #pragma unroll
        for (int p = 0; p < 4; ++p) {
            float v0 = Wf[(8 * g + 2 * p)          * NPROP + ct * 16 + li];
            float v1 = Wf[(8 * g + 2 * p + 1)      * NPROP + ct * 16 + li];
            float u0 = Wf[(32 + 8 * g + 2 * p)     * NPROP + ct * 16 + li];
            float u1 = Wf[(32 + 8 * g + 2 * p + 1) * NPROP + ct * 16 + li];
            unsigned h0 = b16rne(v0), h1 = b16rne(v1);
            unsigned k0 = b16rne(u0), k1 = b16rne(u1);
            whA[p] = h0 | (h1 << 16);
            whB[p] = k0 | (k1 << 16);
            wlA[p] = b16rne(v0 - fromb16(h0)) | (b16rne(v1 - fromb16(h1)) << 16);
            wlB[p] = b16rne(u0 - fromb16(k0)) | (b16rne(u1 - fromb16(k1)) << 16);
        }
        union { uint4 u; short8 s; } WA, WB, LA, LB;
        WA.u = make_uint4(whA[0], whA[1], whA[2], whA[3]);
        WB.u = make_uint4(whB[0], whB[1], whB[2], whB[3]);
        LA.u = make_uint4(wlA[0], wlA[1], wlA[2], wlA[3]);
        LB.u = make_uint4(wlB[0], wlB[1], wlB[2], wlB[3]);
        float bfv = bf[ct * 16 + li];
        f32x4 acc = {bfv, bfv, bfv, bfv};
        acc = __builtin_amdgcn_mfma_f32_16x16x32_bf16(XH01.s, WA.s, acc, 0, 0, 0);
        acc = __builtin_amdgcn_mfma_f32_16x16x32_bf16(XH23.s, WB.s, acc, 0, 0, 0);
        acc = __builtin_amdgcn_mfma_f32_16x16x32_bf16(XL01.s, WA.s, acc, 0, 0, 0);
        acc = __builtin_amdgcn_mfma_f32_16x16x32_bf16(XL23.s, WB.s, acc, 0, 0, 0);
        acc = __builtin_amdgcn_mfma_f32_16x16x32_bf16(XH01.s, LA.s, acc, 0, 0, 0);
        acc = __builtin_amdgcn_mfma_f32_16x16x32_bf16(XH23.s, LB.s, acc, 0, 0, 0);
        #pragma unroll
        for (int e = 0; e < 4; ++e)
            feat[(size_t)(rbase + g * 4 + e) * NPROP + ct * 16 + li] = acc[e];
    }

    {
        unsigned whA[4], whB[4], wlA[4], wlB[4];
        #pragma unroll
        for (int p = 0; p < 4; ++p) {
            float v0 = (li < 4) ? Ws[(8 * g + 2 * p)          * 4 + li] : 0.f;
            float v1 = (li < 4) ? Ws[(8 * g + 2 * p + 1)      * 4 + li] : 0.f;
            float u0 = (li < 4) ? Ws[(32 + 8 * g + 2 * p)     * 4 + li] : 0.f;
            float u1 = (li < 4) ? Ws[(32 + 8 * g + 2 * p + 1) * 4 + li] : 0.f;
            unsigned h0 = b16rne(v0), h1 = b16rne(v1);
            unsigned k0 = b16rne(u0), k1 = b16rne(u1);
            whA[p] = h0 | (h1 << 16);
            whB[p] = k0 | (k1 << 16);
            wlA[p] = b16rne(v0 - fromb16(h0)) | (b16rne(v1 - fromb16(h1)) << 16);
            wlB[p] = b16rne(u0 - fromb16(k0)) | (b16rne(u1 - fromb16(k1)) << 16);
        }
        union { uint4 u; short8 s; } WA, WB, LA, LB;
        WA.u = make_uint4(whA[0], whA[1], whA[2], whA[3]);
        WB.u = make_uint4(whB[0], whB[1], whB[2], whB[3]);
        LA.u = make_uint4(wlA[0], wlA[1], wlA[2], wlA[3]);
        LB.u = make_uint4(wlB[0], wlB[1], wlB[2], wlB[3]);
        float bsv = (li < 4) ? bs[li] : 0.f;
        f32x4 acc = {bsv, bsv, bsv, bsv};
        acc = __builtin_amdgcn_mfma_f32_16x16x32_bf16(XH01.s, WA.s, acc, 0, 0, 0);
        acc = __builtin_amdgcn_mfma_f32_16x16x32_bf16(XH23.s, WB.s, acc, 0, 0, 0);
        acc = __builtin_amdgcn_mfma_f32_16x16x32_bf16(XL01.s, WA.s, acc, 0, 0, 0);
        acc = __builtin_amdgcn_mfma_f32_16x16x32_bf16(XL23.s, WB.s, acc, 0, 0, 0);
        acc = __builtin_amdgcn_mfma_f32_16x16x32_bf16(XH01.s, LA.s, acc, 0, 0, 0);
        acc = __builtin_amdgcn_mfma_f32_16x16x32_bf16(XH23.s, LB.s, acc, 0, 0, 0);
        if (li < 4) {
            #pragma unroll
            for (int e = 0; e < 4; ++e) clds[wv][g * 4 + e][li] = acc[e];
        }
    }
    __syncthreads();

    if (lane < 16) {
        int row = rbase + lane;
        float c0 = clds[wv][lane][0], c1 = clds[wv][lane][1];
        float c2 = clds[wv][lane][2], c3 = clds[wv][lane][3];
        unsigned h0 = b16rne(c0), h1 = b16rne(c1), h2 = b16rne(c2), h3 = b16rne(c3);
        unsigned l0 = b16rne(c0 - fromb16(h0)), l1 = b16rne(c1 - fromb16(h1));
        unsigned l2 = b16rne(c2 - fromb16(h2)), l3 = b16rne(c3 - fromb16(h3));
        float n = c0 * c0; n = fmaf(c1, c1, n); n = fmaf(c2, c2, n); n = fmaf(c3, c3, n);
        unsigned nih = b16rne(n), nil = b16rne(n - fromb16(nih));
        unsigned v0 = h0 | (h1 << 16), v1 = h2 | (h3 << 16);
        unsigned v4 = l0 | (l1 << 16), v5 = l2 | (l3 << 16);
        Bpk[(size_t)row * 2 + 0] = make_uint4(v0, v1, v0, v1);
        Bpk[(size_t)row * 2 + 1] = make_uint4(v4, v5, 0x3F803F80u, nih | (nil << 16));
    }
}

// ---------------- K2: 32x32x16-MFMA KNN top-40 + fused output GEMM --------
// FROZEN R19 state: validated 61.2us, absmax 0.015625. XCD-aware bid remap
// (batch pinned per XCD -> feat L2-resident; FETCH 20.9 -> 7.6 MB).
__global__ __launch_bounds__(1024, 8) void k2_knn(
    const uint4* __restrict__ Bpk, const float* __restrict__ feat,
    const float* __restrict__ x, const unsigned short* __restrict__ Wpk,
    const float* __restrict__ bo, float* __restrict__ out)
{
    __shared__ unsigned minlds[32][132];      // 16896 B
    __shared__ unsigned survK[32][CAPP];      // 22528 B
    __shared__ unsigned taulds[32];
    __shared__ int      cnt[32];
    __shared__ unsigned winC[32][KSEL];       //  5120 B
    __shared__ unsigned short Upk[32][392];   // 25088 B

    int tid = threadIdx.x, w = tid >> 6, lane = tid & 63;
    int bid   = blockIdx.x;
    int xcd   = bid & 7;
    int b     = xcd & 3;                      // batch pinned per XCD
    int strip = (bid >> 3) * 2 + (xcd >> 2);
    int q0    = strip * 32;
    int col = lane & 31, h = lane >> 5;
    int g = lane >> 4, li = lane & 15;        // epilogue indices (16x16x32 D)
    size_t pbase = (size_t)b * N_;

    if (tid < 32) cnt[tid] = 0;

    // A fragment: query q0+col, k-half h
    short8 afr;
    {
        uint4 u0 = Bpk[(pbase + q0 + col) * 2 + 0];
        uint4 u1 = Bpk[(pbase + q0 + col) * 2 + 1];
        union { uint4 u; short8 s; } cv;
        cv.u = (h == 0) ? make_uint4(neg2pk(u0.x), neg2pk(u0.y), neg2pk(u1.x), neg2pk(u1.y))
                        : make_uint4(neg2pk(u0.x), neg2pk(u0.y), u1.w, u1.z);
        afr = cv.s;
    }

    const uint4* bp = Bpk + (pbase + w * 256 + col) * 2 + h;

    // ---- pass 1: MFMA + per-row float minima (8 tiles, 2-deep prefetch) --
    float fm[16];
    #pragma unroll
    for (int r = 0; r < 16; ++r) fm[r] = 1e30f;
    uint4 nb0 = bp[0], nb1 = bp[64];
    #pragma unroll
    for (int t = 0; t < 8; ++t) {
        union { uint4 u; short8 s; } bvv; bvv.u = nb0;
        nb0 = nb1;
        if (t + 2 < 8) nb1 = bp[(t + 2) * 64];
        f32x16 d = __builtin_amdgcn_mfma_f32_32x32x16_bf16(afr, bvv.s, (f32x16){0.f}, 0, 0, 0);
        #pragma unroll
        for (int r = 0; r < 16; ++r) fm[r] = fminf(fm[r], d[r]);
    }
    #pragma unroll
    for (int r = 0; r < 16; ++r) {
        float v = fm[r];
        v = fminf(v, __shfl_xor(v, 8));
        v = fminf(v, __shfl_xor(v, 16));
        fm[r] = v;
    }
    if ((lane & 24) == 0) {
        #pragma unroll
        for (int r = 0; r < 16; ++r) {
            int row = (r & 3) + 8 * (r >> 2) + 4 * h;
            minlds[row][w * 8 + (lane & 7)] = __float_as_uint(fmaxf(fm[r], 0.0f));
        }
    }
    __syncthreads();

    // ---- tau: merge 128 -> 64 group minima, bitonic-64, take #39 ----
    unsigned sv[2];
    #pragma unroll
    for (int e = 0; e < 2; ++e) {
        int r = 2 * w + e;
        sv[e] = min(minlds[r][lane], minlds[r][64 + lane]);
    }
    #pragma unroll
    for (int k = 2; k <= 64; k <<= 1) {
        #pragma unroll
        for (int j2 = k >> 1; j2 >= 1; j2 >>= 1) {
            bool up = (((lane & k) == 0) == ((lane & j2) == 0));
            #pragma unroll
            for (int e = 0; e < 2; ++e) {
                unsigned o = (unsigned)__shfl_xor((int)sv[e], j2);
                sv[e] = up ? min(sv[e], o) : max(sv[e], o);
            }
        }
    }
    if (lane == 39) {
        taulds[2 * w]     = (sv[0] & 0xFFFFF000u) | 0xFFFu;
        taulds[2 * w + 1] = (sv[1] & 0xFFFFF000u) | 0xFFFu;
    }
    __syncthreads();

    float tauF[16];
    #pragma unroll
    for (int r = 0; r < 16; ++r)
        tauF[r] = __uint_as_float(taulds[(r & 3) + 8 * (r >> 2) + 4 * h]);

    // hoisted: x rows for P4a + epilogue bias (in flight across pass2+rank)
    float xpre0 = x[(pbase + q0 + 2 * w) * FIN + lane];
    float xpre1 = x[(pbase + q0 + 2 * w + 1) * FIN + lane];
    float bb    = bo[(w & 7) * 16 + li];

    bool selfDiag = (h == ((col >> 2) & 1));
    int  rs       = ((col >> 3) << 2) | (col & 3);
    int  tdiag    = (w == (strip >> 3)) ? (strip & 7) : 99;    // uniform per wave

    // ---- pass 2: re-stream via MFMA (2-deep prefetch), float-cmp drain ----
    nb0 = bp[0]; nb1 = bp[64];
    #pragma unroll
    for (int t = 0; t < 8; ++t) {
        union { uint4 u; short8 s; } bvv; bvv.u = nb0;
        nb0 = nb1;
        if (t + 2 < 8) nb1 = bp[(t + 2) * 64];
        f32x16 d = __builtin_amdgcn_mfma_f32_32x32x16_bf16(afr, bvv.s, (f32x16){0.f}, 0, 0, 0);
        unsigned idx = (unsigned)((w * 8 + t) * 32 + col);
        if (t == tdiag) {                                      // uniform: diag tile
            #pragma unroll
            for (int r = 0; r < 16; ++r) {
                int rowc = (r & 3) + 8 * (r >> 2) + 4 * h;
                if (selfDiag && r == rs) {                     // self -> rank 0
                    int s = atomicAdd(&cnt[rowc], 1); if (s < CAP) survK[rowc][s] = 0u;
                } else if (d[r] <= tauF[r]) {
                    unsigned c = (__float_as_uint(fmaxf(d[r], 0.f)) & 0xFFFFF000u) | idx;
                    int s = atomicAdd(&cnt[rowc], 1); if (s < CAP) survK[rowc][s] = c;
                }
            }
        } else {
            #pragma unroll
            for (int r = 0; r < 16; ++r) {
                if (d[r] <= tauF[r]) {
                    int rowc = (r & 3) + 8 * (r >> 2) + 4 * h;
                    unsigned c = (__float_as_uint(fmaxf(d[r], 0.f)) & 0xFFFFF000u) | idx;
                    int s = atomicAdd(&cnt[rowc], 1); if (s < CAP) survK[rowc][s] = c;
                }
            }
        }
    }
    __syncthreads();

    // ---- rank survivors; ranks 1..39 -> winners (2 rows per wave) ----
    #pragma unroll
    for (int e = 0; e < 2; ++e) {
        int r = 2 * w + e;
        int S = min(cnt[r], CAP);
        if (lane < 16) survK[r][S + lane] = 0xFFFFFFFFu;       // sentinels
        for (int rr = lane; rr < S; rr += 64) {
            unsigned my = survK[r][rr];
            int c = 0;
            int S4 = (S + 3) >> 2;
            for (int s4 = 0; s4 < S4; ++s4) {
                uint4 u4 = *reinterpret_cast<const uint4*>(&survK[r][4 * s4]);
                c += (u4.x < my) + (u4.y < my) + (u4.z < my) + (u4.w < my);
            }
            if (c >= 1 && c < KSEL) winC[r][c - 1] = my;
        }
    }
    // no barrier: P4 consumes only this wave's own rows (LDS same-wave RAW)

    // ---- P4a: x hi/lo pack (full wave per row, loads hoisted) ----
    {
        unsigned xh0 = b16rne(xpre0), xl0 = b16rne(xpre0 - fromb16(xh0));
        unsigned xh1 = b16rne(xpre1), xl1 = b16rne(xpre1 - fromb16(xh1));
        Upk[2 * w][lane]           = (unsigned short)xh0;
        Upk[2 * w][192 + lane]     = (unsigned short)xl0;
        Upk[2 * w + 1][lane]       = (unsigned short)xh1;
        Upk[2 * w + 1][192 + lane] = (unsigned short)xl1;
    }

    // ---- P4b: neighbor-parallel aggregation (4 groups of 16 lanes) ----
    {
        int l15 = lane & 15;
        int gi  = (lane >> 4) & 1;
        int rw  = 2 * w + (lane >> 5);
        const float4* fr = reinterpret_cast<const float4*>(feat + pbase * NPROP);
        float4 mx4 = make_float4(-3.4e38f, -3.4e38f, -3.4e38f, -3.4e38f);
        float4 sm4 = make_float4(0.f, 0.f, 0.f, 0.f);
        #pragma unroll 4
        for (int i = 0; i < 20; ++i) {
            int n = gi * 20 + i;
            if (n < KSEL - 1) {
                unsigned comp = winC[rw][n];
                int j = (int)(comp & 0xFFFu);
                float dd = __uint_as_float(comp & 0xFFFFF000u);
                float wt = __expf(-10.f * dd);
                float4 f4 = fr[j * 16 + l15];
                float wx = wt * f4.x, wy = wt * f4.y, wz = wt * f4.z, ww = wt * f4.w;
                mx4.x = fmaxf(mx4.x, wx); sm4.x += wx;
                mx4.y = fmaxf(mx4.y, wy); sm4.y += wy;
                mx4.z = fmaxf(mx4.z, wz); sm4.z += wz;
                mx4.w = fmaxf(mx4.w, ww); sm4.w += ww;
            }
        }
        mx4.x = fmaxf(mx4.x, __shfl_xor(mx4.x, 16)); sm4.x += __shfl_xor(sm4.x, 16);
        mx4.y = fmaxf(mx4.y, __shfl_xor(mx4.y, 16)); sm4.y += __shfl_xor(sm4.y, 16);
        mx4.z = fmaxf(mx4.z, __shfl_xor(mx4.z, 16)); sm4.z += __shfl_xor(sm4.z, 16);
        mx4.w = fmaxf(mx4.w, __shfl_xor(mx4.w, 16)); sm4.w += __shfl_xor(sm4.w, 16);

        if (gi == 0) {
            unsigned h0 = b16rne(mx4.x), h1 = b16rne(mx4.y), h2 = b16rne(mx4.z), h3 = b16rne(mx4.w);
            unsigned o0 = b16rne(mx4.x - fromb16(h0)), o1 = b16rne(mx4.y - fromb16(h1));
            unsigned o2 = b16rne(mx4.z - fromb16(h2)), o3 = b16rne(mx4.w - fromb16(h3));
            *reinterpret_cast<uint2*>(&Upk[rw][64  + 4 * l15]) = pk4(h0, h1, h2, h3);
            *reinterpret_cast<uint2*>(&Upk[rw][256 + 4 * l15]) = pk4(o0, o1, o2, o3);
        } else {
            float ex = sm4.x * (1.0f / 39.0f), ey = sm4.y * (1.0f / 39.0f);
            float ez = sm4.z * (1.0f / 39.0f), ew = sm4.w * (1.0f / 39.0f);
            unsigned h0 = b16rne(ex), h1 = b16rne(ey), h2 = b16rne(ez), h3 = b16rne(ew);
            unsigned o0 = b16rne(ex - fromb16(h0)), o1 = b16rne(ey - fromb16(h1));
            unsigned o2 = b16rne(ez - fromb16(h2)), o3 = b16rne(ew - fromb16(h3));
            *reinterpret_cast<uint2*>(&Upk[rw][128 + 4 * l15]) = pk4(h0, h1, h2, h3);
            *reinterpret_cast<uint2*>(&Upk[rw][320 + 4 * l15]) = pk4(o0, o1, o2, o3);
        }
    }
    __syncthreads();

    // ---- epilogue: out[32 x 128] = U @ W_out + b_out; 16 waves, one
    //      16x16 out-tile each ----
    {
        int rh   = w >> 3;
        int colc = (w & 7) * 16 + li;
        const unsigned short* wp = Wpk + (size_t)colc * 576;
        f32x4 oacc = {0.f, 0.f, 0.f, 0.f};
        #pragma unroll
        for (int s = 0; s < 18; ++s) {
            int koff = (s < 6)  ? (32 * s + 8 * g)
                     : (s < 12) ? (192 + 32 * (s - 6) + 8 * g)
                                : (32 * (s - 12) + 8 * g);
            union { uint4 u; short8 s8; } av, bvv;
            av.u  = *reinterpret_cast<const uint4*>(&Upk[rh * 16 + li][koff]);
            bvv.u = *reinterpret_cast<const uint4*>(&wp[32 * s + 8 * g]);
            oacc = __builtin_amdgcn_mfma_f32_16x16x32_bf16(av.s8, bvv.s8, oacc, 0, 0, 0);
        }
        #pragma unroll
        for (int e = 0; e < 4; ++e) {
            int orow = rh * 16 + g * 4 + e;
            out[(size_t)(pbase + q0 + orow) * NFILT + colc] = oacc[e] + bb;
        }
    }
}

extern "C" void kernel_launch(void* const* d_in, const int* in_sizes, int n_in,
                              void* d_out, int out_size, void* d_ws, size_t ws_size,
                              hipStream_t stream)
{
    const float* x  = (const float*)d_in[0];
    const float* Wf = (const float*)d_in[1];
    const float* bf = (const float*)d_in[2];
    const float* Ws = (const float*)d_in[3];
    const float* bs = (const float*)d_in[4];
    const float* Wo = (const float*)d_in[5];
    const float* bo = (const float*)d_in[6];
    float* out = (float*)d_out;

    char* wsb = (char*)d_ws;
    float*          feat = (float*)wsb;                                  // 4 MB
    uint4*          Bpk  = (uint4*)(wsb + (size_t)ROWS * NPROP * 4);     // 512 KB
    unsigned short* Wpk  = (unsigned short*)(wsb + (size_t)ROWS * NPROP * 4
                                                 + (size_t)ROWS * 32);   // 144 KB

    k01_proj<<<384, 256, 0, stream>>>(x, Wf, bf, Ws, bs, Wo, feat, Bpk, Wpk);
    k2_knn  <<<B_ * 128, 1024, 0, stream>>>(Bpk, feat, x, Wpk, bo, out);
}

// Round 22
// 67.477 us; speedup vs baseline: 1.1017x; 1.0333x over previous
//
#include <hip/hip_runtime.h>
#include <hip/hip_bf16.h>
#include <stdint.h>

#define B_    4
#define N_    4096
#define FIN   64
#define NPROP 64
#define NFILT 128
#define KSEL  40
#define ROWS  (B_ * N_)
#define CAP   160
#define CAPP  176

typedef __attribute__((ext_vector_type(8)))  short short8;
typedef __attribute__((ext_vector_type(4)))  float f32x4;
typedef __attribute__((ext_vector_type(16))) float f32x16;

__device__ __forceinline__ unsigned b16rne(float v) {
    unsigned u = __float_as_uint(v);
    return (u + 0x7FFFu + ((u >> 16) & 1u)) >> 16;
}
__device__ __forceinline__ float fromb16(unsigned h) {
    return __uint_as_float(h << 16);
}
// multiply both packed bf16 halves by -2 (sign flip + exponent+1); exact
__device__ __forceinline__ unsigned neg2pk(unsigned p) {
    return (p + 0x00800080u) ^ 0x80008000u;
}
__device__ __forceinline__ uint2 pk4(unsigned a, unsigned b, unsigned c, unsigned d) {
    return make_uint2(a | (b << 16), c | (d << 16));
}

// ---------------- K01: merged projections + W_out pack --------------------
// blocks 0..255  : k1 MFMA projections (validated math), W frags inline.
// blocks 256..383: Wpk pack (consumed only by k2 -> no race).
__global__ __launch_bounds__(256) void k01_proj(
    const float* __restrict__ x,  const float* __restrict__ Wf,
    const float* __restrict__ bf, const float* __restrict__ Ws,
    const float* __restrict__ bs, const float* __restrict__ Wo,
    float* __restrict__ feat, uint4* __restrict__ Bpk,
    unsigned short* __restrict__ Wpk)
{
    int bid = blockIdx.x;

    if (bid >= 256) {                        // ---- Wpk pack ----
        int c = bid - 256, k = threadIdx.x;
        if (k < 192) {
            float wv2 = Wo[k * NFILT + c];
            unsigned wh = b16rne(wv2);
            unsigned wl = b16rne(wv2 - fromb16(wh));
            Wpk[(size_t)c * 576 + k]       = (unsigned short)wh;
            Wpk[(size_t)c * 576 + 192 + k] = (unsigned short)wh;
            Wpk[(size_t)c * 576 + 384 + k] = (unsigned short)wl;
        }
        return;
    }

    // ---- k1 projections (4 waves x 16 rows) ----
    __shared__ float clds[4][16][20];
    int wv = threadIdx.x >> 6, lane = threadIdx.x & 63;
    int li = lane & 15, g = lane >> 4;
    int rbase = bid * 64 + wv * 16;

    const float* xr = x + (size_t)(rbase + li) * FIN + 8 * g;
    float4 a0 = *reinterpret_cast<const float4*>(xr);
    float4 a1 = *reinterpret_cast<const float4*>(xr + 4);
    float4 b0 = *reinterpret_cast<const float4*>(xr + 32);
    float4 b1 = *reinterpret_cast<const float4*>(xr + 36);

    float av[8] = {a0.x, a0.y, a0.z, a0.w, a1.x, a1.y, a1.z, a1.w};
    float bv[8] = {b0.x, b0.y, b0.z, b0.w, b1.x, b1.y, b1.z, b1.w};
    unsigned xh01u[4], xl01u[4], xh23u[4], xl23u[4];
    #pragma unroll
    for (int p = 0; p < 4; ++p) {
        unsigned h0 = b16rne(av[2 * p]), h1 = b16rne(av[2 * p + 1]);
        xh01u[p] = h0 | (h1 << 16);
        xl01u[p] = b16rne(av[2 * p] - fromb16(h0)) | (b16rne(av[2 * p + 1] - fromb16(h1)) << 16);
        unsigned g0 = b16rne(bv[2 * p]), g1 = b16rne(bv[2 * p + 1]);
        xh23u[p] = g0 | (g1 << 16);
        xl23u[p] = b16rne(bv[2 * p] - fromb16(g0)) | (b16rne(bv[2 * p + 1] - fromb16(g1)) << 16);
    }
    union { uint4 u; short8 s; } XH01, XL01, XH23, XL23;
    XH01.u = make_uint4(xh01u[0], xh01u[1], xh01u[2], xh01u[3]);
    XL01.u = make_uint4(xl01u[0], xl01u[1], xl01u[2], xl01u[3]);
    XH23.u = make_uint4(xh23u[0], xh23u[1], xh23u[2], xh23u[3]);
    XL23.u = make_uint4(xl23u[0], xl23u[1], xl23u[2], xl23u[3]);

    #pragma unroll 1
    for (int ct = 0; ct < 4; ++ct) {
        unsigned whA[4], whB[4], wlA[4], wlB[4];
        #pragma unroll
        for (int p = 0; p < 4; ++p) {
            float v0 = Wf[(8 * g + 2 * p)          * NPROP + ct * 16 + li];
            float v1 = Wf[(8 * g + 2 * p + 1)      * NPROP + ct * 16 + li];
            float u0 = Wf[(32 + 8 * g + 2 * p)     * NPROP + ct * 16 + li];
            float u1 = Wf[(32 + 8 * g + 2 * p + 1) * NPROP + ct * 16 + li];
            unsigned h0 = b16rne(v0), h1 = b16rne(v1);
            unsigned k0 = b16rne(u0), k1 = b16rne(u1);
            whA[p] = h0 | (h1 << 16);
            whB[p] = k0 | (k1 << 16);
            wlA[p] = b16rne(v0 - fromb16(h0)) | (b16rne(v1 - fromb16(h1)) << 16);
            wlB[p] = b16rne(u0 - fromb16(k0)) | (b16rne(u1 - fromb16(k1)) << 16);
        }
        union { uint4 u; short8 s; } WA, WB, LA, LB;
        WA.u = make_uint4(whA[0], whA[1], whA[2], whA[3]);
        WB.u = make_uint4(whB[0], whB[1], whB[2], whB[3]);
        LA.u = make_uint4(wlA[0], wlA[1], wlA[2], wlA[3]);
        LB.u = make_uint4(wlB[0], wlB[1], wlB[2], wlB[3]);
        float bfv = bf[ct * 16 + li];
        f32x4 acc = {bfv, bfv, bfv, bfv};
        acc = __builtin_amdgcn_mfma_f32_16x16x32_bf16(XH01.s, WA.s, acc, 0, 0, 0);
        acc = __builtin_amdgcn_mfma_f32_16x16x32_bf16(XH23.s, WB.s, acc, 0, 0, 0);
        acc = __builtin_amdgcn_mfma_f32_16x16x32_bf16(XL01.s, WA.s, acc, 0, 0, 0);
        acc = __builtin_amdgcn_mfma_f32_16x16x32_bf16(XL23.s, WB.s, acc, 0, 0, 0);
        acc = __builtin_amdgcn_mfma_f32_16x16x32_bf16(XH01.s, LA.s, acc, 0, 0, 0);
        acc = __builtin_amdgcn_mfma_f32_16x16x32_bf16(XH23.s, LB.s, acc, 0, 0, 0);
        #pragma unroll
        for (int e = 0; e < 4; ++e)
            feat[(size_t)(rbase + g * 4 + e) * NPROP + ct * 16 + li] = acc[e];
    }

    {
        unsigned whA[4], whB[4], wlA[4], wlB[4];
        #pragma unroll
        for (int p = 0; p < 4; ++p) {
            float v0 = (li < 4) ? Ws[(8 * g + 2 * p)          * 4 + li] : 0.f;
            float v1 = (li < 4) ? Ws[(8 * g + 2 * p + 1)      * 4 + li] : 0.f;
            float u0 = (li < 4) ? Ws[(32 + 8 * g + 2 * p)     * 4 + li] : 0.f;
            float u1 = (li < 4) ? Ws[(32 + 8 * g + 2 * p + 1) * 4 + li] : 0.f;
            unsigned h0 = b16rne(v0), h1 = b16rne(v1);
            unsigned k0 = b16rne(u0), k1 = b16rne(u1);
            whA[p] = h0 | (h1 << 16);
            whB[p] = k0 | (k1 << 16);
            wlA[p] = b16rne(v0 - fromb16(h0)) | (b16rne(v1 - fromb16(h1)) << 16);
            wlB[p] = b16rne(u0 - fromb16(k0)) | (b16rne(u1 - fromb16(k1)) << 16);
        }
        union { uint4 u; short8 s; } WA, WB, LA, LB;
        WA.u = make_uint4(whA[0], whA[1], whA[2], whA[3]);
        WB.u = make_uint4(whB[0], whB[1], whB[2], whB[3]);
        LA.u = make_uint4(wlA[0], wlA[1], wlA[2], wlA[3]);
        LB.u = make_uint4(wlB[0], wlB[1], wlB[2], wlB[3]);
        float bsv = (li < 4) ? bs[li] : 0.f;
        f32x4 acc = {bsv, bsv, bsv, bsv};
        acc = __builtin_amdgcn_mfma_f32_16x16x32_bf16(XH01.s, WA.s, acc, 0, 0, 0);
        acc = __builtin_amdgcn_mfma_f32_16x16x32_bf16(XH23.s, WB.s, acc, 0, 0, 0);
        acc = __builtin_amdgcn_mfma_f32_16x16x32_bf16(XL01.s, WA.s, acc, 0, 0, 0);
        acc = __builtin_amdgcn_mfma_f32_16x16x32_bf16(XL23.s, WB.s, acc, 0, 0, 0);
        acc = __builtin_amdgcn_mfma_f32_16x16x32_bf16(XH01.s, LA.s, acc, 0, 0, 0);
        acc = __builtin_amdgcn_mfma_f32_16x16x32_bf16(XH23.s, LB.s, acc, 0, 0, 0);
        if (li < 4) {
            #pragma unroll
            for (int e = 0; e < 4; ++e) clds[wv][g * 4 + e][li] = acc[e];
        }
    }
    __syncthreads();

    if (lane < 16) {
        int row = rbase + lane;
        float c0 = clds[wv][lane][0], c1 = clds[wv][lane][1];
        float c2 = clds[wv][lane][2], c3 = clds[wv][lane][3];
        unsigned h0 = b16rne(c0), h1 = b16rne(c1), h2 = b16rne(c2), h3 = b16rne(c3);
        unsigned l0 = b16rne(c0 - fromb16(h0)), l1 = b16rne(c1 - fromb16(h1));
        unsigned l2 = b16rne(c2 - fromb16(h2)), l3 = b16rne(c3 - fromb16(h3));
        float n = c0 * c0; n = fmaf(c1, c1, n); n = fmaf(c2, c2, n); n = fmaf(c3, c3, n);
        unsigned nih = b16rne(n), nil = b16rne(n - fromb16(nih));
        unsigned v0 = h0 | (h1 << 16), v1 = h2 | (h3 << 16);
        unsigned v4 = l0 | (l1 << 16), v5 = l2 | (l3 << 16);
        Bpk[(size_t)row * 2 + 0] = make_uint4(v0, v1, v0, v1);
        Bpk[(size_t)row * 2 + 1] = make_uint4(v4, v5, 0x3F803F80u, nih | (nil << 16));
    }
}

// ---------------- K2: 32x32x16-MFMA KNN top-40 + fused output GEMM --------
// EXACT R19 state (validated 61.2us k2 / 67.6us total, absmax 0.015625):
// XCD-aware bid remap; NO value hoisting across pass 2 (spill canary).
__global__ __launch_bounds__(1024, 8) void k2_knn(
    const uint4* __restrict__ Bpk, const float* __restrict__ feat,
    const float* __restrict__ x, const unsigned short* __restrict__ Wpk,
    const float* __restrict__ bo, float* __restrict__ out)
{
    __shared__ unsigned minlds[32][132];      // 16896 B
    __shared__ unsigned survK[32][CAPP];      // 22528 B
    __shared__ unsigned taulds[32];
    __shared__ int      cnt[32];
    __shared__ unsigned winC[32][KSEL];       //  5120 B
    __shared__ unsigned short Upk[32][392];   // 25088 B

    int tid = threadIdx.x, w = tid >> 6, lane = tid & 63;
    int bid   = blockIdx.x;
    int xcd   = bid & 7;
    int b     = xcd & 3;                      // batch pinned per XCD
    int strip = (bid >> 3) * 2 + (xcd >> 2);
    int q0    = strip * 32;
    int col = lane & 31, h = lane >> 5;
    int g = lane >> 4, li = lane & 15;        // epilogue indices (16x16x32 D)
    size_t pbase = (size_t)b * N_;

    if (tid < 32) cnt[tid] = 0;

    // A fragment: query q0+col, k-half h
    short8 afr;
    {
        uint4 u0 = Bpk[(pbase + q0 + col) * 2 + 0];
        uint4 u1 = Bpk[(pbase + q0 + col) * 2 + 1];
        union { uint4 u; short8 s; } cv;
        cv.u = (h == 0) ? make_uint4(neg2pk(u0.x), neg2pk(u0.y), neg2pk(u1.x), neg2pk(u1.y))
                        : make_uint4(neg2pk(u0.x), neg2pk(u0.y), u1.w, u1.z);
        afr = cv.s;
    }

    const uint4* bp = Bpk + (pbase + w * 256 + col) * 2 + h;

    // ---- pass 1: MFMA + per-row float minima (8 tiles, 2-deep prefetch) --
    float fm[16];
    #pragma unroll
    for (int r = 0; r < 16; ++r) fm[r] = 1e30f;
    uint4 nb0 = bp[0], nb1 = bp[64];
    #pragma unroll
    for (int t = 0; t < 8; ++t) {
        union { uint4 u; short8 s; } bvv; bvv.u = nb0;
        nb0 = nb1;
        if (t + 2 < 8) nb1 = bp[(t + 2) * 64];
        f32x16 d = __builtin_amdgcn_mfma_f32_32x32x16_bf16(afr, bvv.s, (f32x16){0.f}, 0, 0, 0);
        #pragma unroll
        for (int r = 0; r < 16; ++r) fm[r] = fminf(fm[r], d[r]);
    }
    #pragma unroll
    for (int r = 0; r < 16; ++r) {
        float v = fm[r];
        v = fminf(v, __shfl_xor(v, 8));
        v = fminf(v, __shfl_xor(v, 16));
        fm[r] = v;
    }
    if ((lane & 24) == 0) {
        #pragma unroll
        for (int r = 0; r < 16; ++r) {
            int row = (r & 3) + 8 * (r >> 2) + 4 * h;
            minlds[row][w * 8 + (lane & 7)] = __float_as_uint(fmaxf(fm[r], 0.0f));
        }
    }
    __syncthreads();

    // ---- tau: merge 128 -> 64 group minima, bitonic-64, take #39 ----
    unsigned sv[2];
    #pragma unroll
    for (int e = 0; e < 2; ++e) {
        int r = 2 * w + e;
        sv[e] = min(minlds[r][lane], minlds[r][64 + lane]);
    }
    #pragma unroll
    for (int k = 2; k <= 64; k <<= 1) {
        #pragma unroll
        for (int j2 = k >> 1; j2 >= 1; j2 >>= 1) {
            bool up = (((lane & k) == 0) == ((lane & j2) == 0));
            #pragma unroll
            for (int e = 0; e < 2; ++e) {
                unsigned o = (unsigned)__shfl_xor((int)sv[e], j2);
                sv[e] = up ? min(sv[e], o) : max(sv[e], o);
            }
        }
    }
    if (lane == 39) {
        taulds[2 * w]     = (sv[0] & 0xFFFFF000u) | 0xFFFu;
        taulds[2 * w + 1] = (sv[1] & 0xFFFFF000u) | 0xFFFu;
    }
    __syncthreads();

    float tauF[16];
    #pragma unroll
    for (int r = 0; r < 16; ++r)
        tauF[r] = __uint_as_float(taulds[(r & 3) + 8 * (r >> 2) + 4 * h]);

    bool selfDiag = (h == ((col >> 2) & 1));
    int  rs       = ((col >> 3) << 2) | (col & 3);
    int  tdiag    = (w == (strip >> 3)) ? (strip & 7) : 99;    // uniform per wave

    // ---- pass 2: re-stream via MFMA (2-deep prefetch), float-cmp drain ----
    nb0 = bp[0]; nb1 = bp[64];
    #pragma unroll
    for (int t = 0; t < 8; ++t) {
        union { uint4 u; short8 s; } bvv; bvv.u = nb0;
        nb0 = nb1;
        if (t + 2 < 8) nb1 = bp[(t + 2) * 64];
        f32x16 d = __builtin_amdgcn_mfma_f32_32x32x16_bf16(afr, bvv.s, (f32x16){0.f}, 0, 0, 0);
        unsigned idx = (unsigned)((w * 8 + t) * 32 + col);
        if (t == tdiag) {                                      // uniform: diag tile
            #pragma unroll
            for (int r = 0; r < 16; ++r) {
                int rowc = (r & 3) + 8 * (r >> 2) + 4 * h;
                if (selfDiag && r == rs) {                     // self -> rank 0
                    int s = atomicAdd(&cnt[rowc], 1); if (s < CAP) survK[rowc][s] = 0u;
                } else if (d[r] <= tauF[r]) {
                    unsigned c = (__float_as_uint(fmaxf(d[r], 0.f)) & 0xFFFFF000u) | idx;
                    int s = atomicAdd(&cnt[rowc], 1); if (s < CAP) survK[rowc][s] = c;
                }
            }
        } else {
            #pragma unroll
            for (int r = 0; r < 16; ++r) {
                if (d[r] <= tauF[r]) {
                    int rowc = (r & 3) + 8 * (r >> 2) + 4 * h;
                    unsigned c = (__float_as_uint(fmaxf(d[r], 0.f)) & 0xFFFFF000u) | idx;
                    int s = atomicAdd(&cnt[rowc], 1); if (s < CAP) survK[rowc][s] = c;
                }
            }
        }
    }
    __syncthreads();

    // ---- rank survivors; ranks 1..39 -> winners (2 rows per wave) ----
    #pragma unroll
    for (int e = 0; e < 2; ++e) {
        int r = 2 * w + e;
        int S = min(cnt[r], CAP);
        if (lane < 16) survK[r][S + lane] = 0xFFFFFFFFu;       // sentinels
        for (int rr = lane; rr < S; rr += 64) {
            unsigned my = survK[r][rr];
            int c = 0;
            int S4 = (S + 3) >> 2;
            for (int s4 = 0; s4 < S4; ++s4) {
                uint4 u4 = *reinterpret_cast<const uint4*>(&survK[r][4 * s4]);
                c += (u4.x < my) + (u4.y < my) + (u4.z < my) + (u4.w < my);
            }
            if (c >= 1 && c < KSEL) winC[r][c - 1] = my;
        }
    }
    // no barrier: P4 consumes only this wave's own rows (LDS same-wave RAW)

    // ---- P4a: x hi/lo pack (full wave per row) ----
    #pragma unroll
    for (int e = 0; e < 2; ++e) {
        int r = 2 * w + e;
        float xv = x[(pbase + q0 + r) * FIN + lane];
        unsigned xh = b16rne(xv), xl = b16rne(xv - fromb16(xh));
        Upk[r][lane]       = (unsigned short)xh;
        Upk[r][192 + lane] = (unsigned short)xl;
    }

    // ---- P4b: neighbor-parallel aggregation (4 groups of 16 lanes) ----
    {
        int l15 = lane & 15;
        int gi  = (lane >> 4) & 1;
        int rw  = 2 * w + (lane >> 5);
        const float4* fr = reinterpret_cast<const float4*>(feat + pbase * NPROP);
        float4 mx4 = make_float4(-3.4e38f, -3.4e38f, -3.4e38f, -3.4e38f);
        float4 sm4 = make_float4(0.f, 0.f, 0.f, 0.f);
        #pragma unroll 4
        for (int i = 0; i < 20; ++i) {
            int n = gi * 20 + i;
            if (n < KSEL - 1) {
                unsigned comp = winC[rw][n];
                int j = (int)(comp & 0xFFFu);
                float dd = __uint_as_float(comp & 0xFFFFF000u);
                float wt = __expf(-10.f * dd);
                float4 f4 = fr[j * 16 + l15];
                float wx = wt * f4.x, wy = wt * f4.y, wz = wt * f4.z, ww = wt * f4.w;
                mx4.x = fmaxf(mx4.x, wx); sm4.x += wx;
                mx4.y = fmaxf(mx4.y, wy); sm4.y += wy;
                mx4.z = fmaxf(mx4.z, wz); sm4.z += wz;
                mx4.w = fmaxf(mx4.w, ww); sm4.w += ww;
            }
        }
        mx4.x = fmaxf(mx4.x, __shfl_xor(mx4.x, 16)); sm4.x += __shfl_xor(sm4.x, 16);
        mx4.y = fmaxf(mx4.y, __shfl_xor(mx4.y, 16)); sm4.y += __shfl_xor(sm4.y, 16);
        mx4.z = fmaxf(mx4.z, __shfl_xor(mx4.z, 16)); sm4.z += __shfl_xor(sm4.z, 16);
        mx4.w = fmaxf(mx4.w, __shfl_xor(mx4.w, 16)); sm4.w += __shfl_xor(sm4.w, 16);

        if (gi == 0) {
            unsigned h0 = b16rne(mx4.x), h1 = b16rne(mx4.y), h2 = b16rne(mx4.z), h3 = b16rne(mx4.w);
            unsigned o0 = b16rne(mx4.x - fromb16(h0)), o1 = b16rne(mx4.y - fromb16(h1));
            unsigned o2 = b16rne(mx4.z - fromb16(h2)), o3 = b16rne(mx4.w - fromb16(h3));
            *reinterpret_cast<uint2*>(&Upk[rw][64  + 4 * l15]) = pk4(h0, h1, h2, h3);
            *reinterpret_cast<uint2*>(&Upk[rw][256 + 4 * l15]) = pk4(o0, o1, o2, o3);
        } else {
            float ex = sm4.x * (1.0f / 39.0f), ey = sm4.y * (1.0f / 39.0f);
            float ez = sm4.z * (1.0f / 39.0f), ew = sm4.w * (1.0f / 39.0f);
            unsigned h0 = b16rne(ex), h1 = b16rne(ey), h2 = b16rne(ez), h3 = b16rne(ew);
            unsigned o0 = b16rne(ex - fromb16(h0)), o1 = b16rne(ey - fromb16(h1));
            unsigned o2 = b16rne(ez - fromb16(h2)), o3 = b16rne(ew - fromb16(h3));
            *reinterpret_cast<uint2*>(&Upk[rw][128 + 4 * l15]) = pk4(h0, h1, h2, h3);
            *reinterpret_cast<uint2*>(&Upk[rw][320 + 4 * l15]) = pk4(o0, o1, o2, o3);
        }
    }
    __syncthreads();

    // ---- epilogue: out[32 x 128] = U @ W_out + b_out; 16 waves, one
    //      16x16 out-tile each ----
    {
        int rh   = w >> 3;
        int colc = (w & 7) * 16 + li;
        const unsigned short* wp = Wpk + (size_t)colc * 576;
        f32x4 oacc = {0.f, 0.f, 0.f, 0.f};
        #pragma unroll
        for (int s = 0; s < 18; ++s) {
            int koff = (s < 6)  ? (32 * s + 8 * g)
                     : (s < 12) ? (192 + 32 * (s - 6) + 8 * g)
                                : (32 * (s - 12) + 8 * g);
            union { uint4 u; short8 s8; } av, bvv;
            av.u  = *reinterpret_cast<const uint4*>(&Upk[rh * 16 + li][koff]);
            bvv.u = *reinterpret_cast<const uint4*>(&wp[32 * s + 8 * g]);
            oacc = __builtin_amdgcn_mfma_f32_16x16x32_bf16(av.s8, bvv.s8, oacc, 0, 0, 0);
        }
        float bb = bo[colc];
        #pragma unroll
        for (int e = 0; e < 4; ++e) {
            int orow = rh * 16 + g * 4 + e;
            out[(size_t)(pbase + q0 + orow) * NFILT + colc] = oacc[e] + bb;
        }
    }
}

extern "C" void kernel_launch(void* const* d_in, const int* in_sizes, int n_in,
                              void* d_out, int out_size, void* d_ws, size_t ws_size,
                              hipStream_t stream)
{
    const float* x  = (const float*)d_in[0];
    const float* Wf = (const float*)d_in[1];
    const float* bf = (const float*)d_in[2];
    const float* Ws = (const float*)d_in[3];
    const float* bs = (const float*)d_in[4];
    const float* Wo = (const float*)d_in[5];
    const float* bo = (const float*)d_in[6];
    float* out = (float*)d_out;

    char* wsb = (char*)d_ws;
    float*          feat = (float*)wsb;                                  // 4 MB
    uint4*          Bpk  = (uint4*)(wsb + (size_t)ROWS * NPROP * 4);     // 512 KB
    unsigned short* Wpk  = (unsigned short*)(wsb + (size_t)ROWS * NPROP * 4
                                                 + (size_t)ROWS * 32);   // 144 KB

    k01_proj<<<384, 256, 0, stream>>>(x, Wf, bf, Ws, bs, Wo, feat, Bpk, Wpk);
    k2_knn  <<<B_ * 128, 1024, 0, stream>>>(Bpk, feat, x, Wpk, bo, out);
}